// Round 9
// baseline (25741.779 us; speedup 1.0000x reference)
//
#include <hip/hip_runtime.h>
#include <hip/hip_bf16.h>

#define HD   1024
#define GD   4096   // 4*H
#define TT   4096
#define NWG  256

using u32x4 = __attribute__((ext_vector_type(4))) unsigned int;

// ---------------------------------------------------------------- gx GEMM
// gx[t][n] = sum_k emb[tokens[t]][k] * Wih[n][k] + bih[n] + bhh[n]
#define BM 128
#define BN 128
#define BK 16
#define LDP 132

__global__ __launch_bounds__(256, 2) void gemm_gx(
    const int* __restrict__ tokens,
    const float* __restrict__ emb,    // VOCAB x HD
    const float* __restrict__ Wih,    // GD x HD
    const float* __restrict__ bih,
    const float* __restrict__ bhh,
    float* __restrict__ gxout)        // TT x GD
{
    __shared__ float As[BK][LDP];
    __shared__ float Bs[BK][LDP];
    const int tid = threadIdx.x;
    const int m0 = blockIdx.x * BM;
    const int n0 = blockIdx.y * BN;
    const int tx = tid & 15;
    const int ty = tid >> 4;

    const int quad = tid & 3;
    const int r0   = tid >> 2;
    const int tok0 = tokens[m0 + r0];
    const int tok1 = tokens[m0 + r0 + 64];

    float acc[8][8] = {};

    for (int kt = 0; kt < HD; kt += BK) {
        float4 av0 = *reinterpret_cast<const float4*>(
            &emb[(size_t)tok0 * HD + kt + quad * 4]);
        float4 bv0 = *reinterpret_cast<const float4*>(
            &Wih[(size_t)(n0 + r0) * HD + kt + quad * 4]);
        float4 av1 = *reinterpret_cast<const float4*>(
            &emb[(size_t)tok1 * HD + kt + quad * 4]);
        float4 bv1 = *reinterpret_cast<const float4*>(
            &Wih[(size_t)(n0 + r0 + 64) * HD + kt + quad * 4]);
        As[quad * 4 + 0][r0] = av0.x;
        As[quad * 4 + 1][r0] = av0.y;
        As[quad * 4 + 2][r0] = av0.z;
        As[quad * 4 + 3][r0] = av0.w;
        Bs[quad * 4 + 0][r0] = bv0.x;
        Bs[quad * 4 + 1][r0] = bv0.y;
        Bs[quad * 4 + 2][r0] = bv0.z;
        Bs[quad * 4 + 3][r0] = bv0.w;
        As[quad * 4 + 0][r0 + 64] = av1.x;
        As[quad * 4 + 1][r0 + 64] = av1.y;
        As[quad * 4 + 2][r0 + 64] = av1.z;
        As[quad * 4 + 3][r0 + 64] = av1.w;
        Bs[quad * 4 + 0][r0 + 64] = bv1.x;
        Bs[quad * 4 + 1][r0 + 64] = bv1.y;
        Bs[quad * 4 + 2][r0 + 64] = bv1.z;
        Bs[quad * 4 + 3][r0 + 64] = bv1.w;
        __syncthreads();
#pragma unroll
        for (int k = 0; k < BK; ++k) {
            float4 a0 = *reinterpret_cast<const float4*>(&As[k][ty * 8]);
            float4 a1 = *reinterpret_cast<const float4*>(&As[k][ty * 8 + 4]);
            float4 b0 = *reinterpret_cast<const float4*>(&Bs[k][tx * 8]);
            float4 b1 = *reinterpret_cast<const float4*>(&Bs[k][tx * 8 + 4]);
            float a[8] = {a0.x, a0.y, a0.z, a0.w, a1.x, a1.y, a1.z, a1.w};
            float b[8] = {b0.x, b0.y, b0.z, b0.w, b1.x, b1.y, b1.z, b1.w};
#pragma unroll
            for (int i = 0; i < 8; ++i)
#pragma unroll
                for (int j = 0; j < 8; ++j)
                    acc[i][j] += a[i] * b[j];
        }
        __syncthreads();
    }

    float bias[8];
#pragma unroll
    for (int j = 0; j < 8; ++j) {
        int n = n0 + tx * 8 + j;
        bias[j] = bih[n] + bhh[n];
    }
#pragma unroll
    for (int i = 0; i < 8; ++i) {
        size_t o = (size_t)(m0 + ty * 8 + i) * GD + n0 + tx * 8;
        float4 s0 = {acc[i][0] + bias[0], acc[i][1] + bias[1],
                     acc[i][2] + bias[2], acc[i][3] + bias[3]};
        float4 s1 = {acc[i][4] + bias[4], acc[i][5] + bias[5],
                     acc[i][6] + bias[6], acc[i][7] + bias[7]};
        *reinterpret_cast<float4*>(&gxout[o]) = s0;
        *reinterpret_cast<float4*>(&gxout[o + 4]) = s1;
    }
}

// ---------------------------------------------------------------- LSTM scan
// 8 XCD-replicas (XCC_ID claim), each 32 WGs x 512 thr (8 waves), 1 WG/CU.
// Wave wv owns h j0..j0+3 (16 gate-rows). Cols span the whole wave:
// lane owns cols {4*lane + 256q + e}. ALL-F32 weights: cols 0..767 in VGPRs
// (192/thread), cols 768..1023 in LDS (128 KB/CU). h f32 in LDS.
// Reduction: 16-lane shfl_xor (proven) + SALU readlane combine over the
// 4 lane-groups. Exchange: r8-proven dual path (L2 sc0 fast, sticky IC
// fallback, timeout exit).
__device__ __forceinline__ float sigmoid_(float x) {
    return 1.f / (1.f + __expf(-x));
}
__device__ __forceinline__ float tanh_(float x) {
    return __builtin_fmaf(2.f, 1.f / (1.f + __expf(-2.f * x)), -1.f);
}
__device__ __forceinline__ void lds_barrier_() {
    asm volatile("s_waitcnt lgkmcnt(0)" ::: "memory");
    __builtin_amdgcn_s_barrier();
}
__device__ __forceinline__ float rl_(float v, int l) {
    return __uint_as_float(__builtin_amdgcn_readlane(__float_as_uint(v), l));
}
__device__ __forceinline__ float dot4_(float4 a, float4 b, float c) {
    c = __builtin_fmaf(a.x, b.x, c);
    c = __builtin_fmaf(a.y, b.y, c);
    c = __builtin_fmaf(a.z, b.z, c);
    return __builtin_fmaf(a.w, b.w, c);
}

__global__ __launch_bounds__(512, 1) void lstm_scan(
    const float* __restrict__ gx,               // TT x GD (includes biases)
    const float* __restrict__ whh,              // GD x HD
    float* __restrict__ out,                    // TT*HD + HD + HD
    unsigned long long* __restrict__ mbF,       // fast: 8 x 2 x 1024 u64
    unsigned long long* __restrict__ mbS,       // fallback: same layout
    int* __restrict__ ctr)                      // 8 claim counters
{
    const int tid  = threadIdx.x;
    const int lane = tid & 63;
    const int wv   = tid >> 6;          // 0..7
    const int sub  = lane >> 4;         // 0..3 (publisher group)
    const int chunk = lane & 15;

    __shared__ int s_role, s_xcd, s_fail;
    __shared__ float wlds[8][16][256];              // 128 KB: cols 768..1023
    __shared__ float h_lds[2][HD];                  // 8 KB

    if (tid == 0) {
        unsigned int x;
        asm volatile("s_getreg_b32 %0, hwreg(20, 0, 32)" : "=s"(x)); // XCC_ID
        x &= 7;
        s_xcd  = (int)x;
        s_role = atomicAdd(&ctr[x], 1);
        s_fail = 0;
    }
    __syncthreads();
    const int role = s_role;
    if (role >= 32) return;             // surplus WG on this XCD

    unsigned long long* const fastb = mbF + (size_t)s_xcd * 2048;
    unsigned long long* const slowb = mbS + (size_t)s_xcd * 2048;
    const int j0 = role * 32 + wv * 4;  // this wave's 4 h elements

    // ---- weights: rows rr=0..15 (g=rr>>2, m=rr&3), cols 4*lane+256q+e ---
    float4 wreg[16][3];
#pragma unroll
    for (int rr = 0; rr < 16; ++rr) {
        const float* wr = whh + (size_t)((rr >> 2) * HD + j0 + (rr & 3)) * HD;
#pragma unroll
        for (int q = 0; q < 3; ++q)
            wreg[rr][q] = *reinterpret_cast<const float4*>(&wr[4 * lane + 256 * q]);
        *reinterpret_cast<float4*>(&wlds[wv][rr][4 * lane]) =
            *reinterpret_cast<const float4*>(&wr[4 * lane + 768]);
    }

    *reinterpret_cast<float2*>(&h_lds[0][2 * tid]) = float2{0.f, 0.f};
    lds_barrier_();

    // gx: lane rr (<16) holds row rr's gx value in one register
    const int grow = (lane >> 2) * HD + j0 + (lane & 3);   // valid lane<16
    float gxc = (lane < 16) ? gx[grow] : 0.f;

    float cst[4] = {0.f, 0.f, 0.f, 0.f};
    bool slow = false;
    const int e0 = 2 * tid;

    for (int s = 1; s <= TT; ++s) {
        const int cb = (s - 1) & 1;
        const int nb = s & 1;

        float gxn = 0.f;
        if (s < TT && lane < 16) gxn = gx[(size_t)s * GD + grow];

        // ---- h fragments (4 x float4, conflict-free contiguous) ---------
        float4 hq0 = *reinterpret_cast<const float4*>(&h_lds[cb][4 * lane]);
        float4 hq1 = *reinterpret_cast<const float4*>(&h_lds[cb][4 * lane + 256]);
        float4 hq2 = *reinterpret_cast<const float4*>(&h_lds[cb][4 * lane + 512]);
        float4 hq3 = *reinterpret_cast<const float4*>(&h_lds[cb][4 * lane + 768]);

        // ---- pass 0: rows 0..7 (gates i, f) -----------------------------
        float ii[4], hh[4];
        {
            float a8[8];
#pragma unroll
            for (int rr = 0; rr < 8; ++rr) {
                float4 wl = *reinterpret_cast<const float4*>(&wlds[wv][rr][4 * lane]);
                float a = dot4_(wreg[rr][0], hq0, 0.f);
                a = dot4_(wreg[rr][1], hq1, a);
                a = dot4_(wreg[rr][2], hq2, a);
                a8[rr] = dot4_(wl, hq3, a);
            }
#pragma unroll
            for (int rr = 0; rr < 8; ++rr) {
                a8[rr] += __shfl_xor(a8[rr], 1, 64);
                a8[rr] += __shfl_xor(a8[rr], 2, 64);
                a8[rr] += __shfl_xor(a8[rr], 4, 64);
                a8[rr] += __shfl_xor(a8[rr], 8, 64);
            }
#pragma unroll
            for (int m = 0; m < 4; ++m) {
                float pi = rl_(a8[m], 0) + rl_(a8[m], 16) +
                           rl_(a8[m], 32) + rl_(a8[m], 48) + rl_(gxc, m);
                float pf = rl_(a8[4 + m], 0) + rl_(a8[4 + m], 16) +
                           rl_(a8[4 + m], 32) + rl_(a8[4 + m], 48) + rl_(gxc, 4 + m);
                ii[m] = sigmoid_(pi);
                cst[m] *= sigmoid_(pf);       // f*c part; +i*g after pass 1
            }
        }
        // ---- pass 1: rows 8..15 (gates g, o) ----------------------------
        {
            float a8[8];
#pragma unroll
            for (int rr = 0; rr < 8; ++rr) {
                float4 wl = *reinterpret_cast<const float4*>(&wlds[wv][8 + rr][4 * lane]);
                float a = dot4_(wreg[8 + rr][0], hq0, 0.f);
                a = dot4_(wreg[8 + rr][1], hq1, a);
                a = dot4_(wreg[8 + rr][2], hq2, a);
                a8[rr] = dot4_(wl, hq3, a);
            }
#pragma unroll
            for (int rr = 0; rr < 8; ++rr) {
                a8[rr] += __shfl_xor(a8[rr], 1, 64);
                a8[rr] += __shfl_xor(a8[rr], 2, 64);
                a8[rr] += __shfl_xor(a8[rr], 4, 64);
                a8[rr] += __shfl_xor(a8[rr], 8, 64);
            }
#pragma unroll
            for (int m = 0; m < 4; ++m) {
                float pg = rl_(a8[m], 0) + rl_(a8[m], 16) +
                           rl_(a8[m], 32) + rl_(a8[m], 48) + rl_(gxc, 8 + m);
                float po = rl_(a8[4 + m], 0) + rl_(a8[4 + m], 16) +
                           rl_(a8[4 + m], 32) + rl_(a8[4 + m], 48) + rl_(gxc, 12 + m);
                cst[m] = __builtin_fmaf(ii[m], tanh_(pg), cst[m]);
                hh[m] = sigmoid_(po) * tanh_(cst[m]);
            }
        }
        gxc = gxn;

        // select this lane-group's published value (static cndmask chain)
        float hpub = (sub == 0) ? hh[0] : (sub == 1) ? hh[1]
                   : (sub == 2) ? hh[2] : hh[3];

        if (s == TT) {
            if (chunk == 0) {
                float cpub = (sub == 0) ? cst[0] : (sub == 1) ? cst[1]
                           : (sub == 2) ? cst[2] : cst[3];
                out[(size_t)(s - 1) * HD + j0 + sub] = hpub;
                out[(size_t)TT * HD + j0 + sub] = hpub;          // h_n
                out[(size_t)TT * HD + HD + j0 + sub] = cpub;     // c_n
            }
            break;
        }

        // ---- dual publish -----------------------------------------------
        const unsigned int us = (unsigned int)s;
        if (chunk == 0) {
            unsigned long long pkt =
                ((unsigned long long)us << 32) | __float_as_uint(hpub);
            __hip_atomic_store(&fastb[(size_t)nb * HD + j0 + sub], pkt,
                               __ATOMIC_RELAXED, __HIP_MEMORY_SCOPE_WORKGROUP);
            __hip_atomic_store(&slowb[(size_t)nb * HD + j0 + sub], pkt,
                               __ATOMIC_RELAXED, __HIP_MEMORY_SCOPE_AGENT);
            out[(size_t)(s - 1) * HD + j0 + sub] = hpub;
        }

        // ---- gather h(s): entries e0, e0+1 ------------------------------
        {
            u32x4 q;
            bool ok = false;
            if (!slow) {
                const unsigned long long* pf = fastb + (size_t)nb * HD + e0;
                for (int r = 0; r < 48 && !ok; ++r) {
                    asm volatile(
                        "global_load_dwordx4 %0, %1, off sc0\n\t"
                        "s_waitcnt vmcnt(0)"
                        : "=v"(q) : "v"(pf) : "memory");
                    ok = (q.y == us) & (q.w == us);
                }
                if (!ok) slow = true;
            }
            if (!ok) {
                const unsigned long long* ps = slowb + (size_t)nb * HD + e0;
                int r = 0;
                for (;;) {
                    unsigned long long v0 = __hip_atomic_load(
                        &ps[0], __ATOMIC_RELAXED, __HIP_MEMORY_SCOPE_AGENT);
                    unsigned long long v1 = __hip_atomic_load(
                        &ps[1], __ATOMIC_RELAXED, __HIP_MEMORY_SCOPE_AGENT);
                    if (((unsigned int)(v0 >> 32) == us) &
                        ((unsigned int)(v1 >> 32) == us)) {
                        q.x = (unsigned int)v0;
                        q.z = (unsigned int)v1;
                        ok = true;
                        break;
                    }
                    ++r;
                    if (r > 8) __builtin_amdgcn_s_sleep(2);
                    if (r > 32768) break;       // dead replica
                }
                if (!ok) s_fail = 1;
            }
            *reinterpret_cast<float2*>(&h_lds[nb][e0]) =
                float2{__uint_as_float(q.x), __uint_as_float(q.z)};
        }
        lds_barrier_();
        if (s_fail) return;              // incomplete replica: exit cleanly
    }
}

// ---------------------------------------------------------------- launch
extern "C" void kernel_launch(void* const* d_in, const int* in_sizes, int n_in,
                              void* d_out, int out_size, void* d_ws, size_t ws_size,
                              hipStream_t stream) {
    const int*   tokens = (const int*)d_in[0];
    const float* emb    = (const float*)d_in[1];
    const float* w_ih   = (const float*)d_in[2];
    const float* w_hh   = (const float*)d_in[3];
    const float* b_ih   = (const float*)d_in[4];
    const float* b_hh   = (const float*)d_in[5];
    float* out = (float*)d_out;

    char* ws = (char*)d_ws;
    unsigned long long* mbF = (unsigned long long*)ws;            // 128 KB
    unsigned long long* mbS = (unsigned long long*)(ws + 131072); // 128 KB
    int* ctr = (int*)(ws + 262144);                               // 32 B
    float* gxbuf = (float*)(ws + (1 << 20));                      // 64 MB

    (void)hipMemsetAsync(ws, 0, 262144 + 4096, stream);
    gemm_gx<<<dim3(TT / BM, GD / BN), 256, 0, stream>>>(tokens, emb, w_ih,
                                                        b_ih, b_hh, gxbuf);
    lstm_scan<<<NWG, 512, 0, stream>>>(gxbuf, w_hh, out, mbF, mbS, ctr);
}